// Round 16
// baseline (515.245 us; speedup 1.0000x reference)
//
#include <hip/hip_runtime.h>
#include <math.h>

typedef __bf16 bf16;
typedef __attribute__((ext_vector_type(4))) __bf16 bf16x4;
typedef __attribute__((ext_vector_type(8))) __bf16 bf16x8;
typedef __attribute__((ext_vector_type(4))) float f32x4;

#define T_STEPS 128
#define B_SZ    256
#define V_SZ    256
#define N_SZ    1024
#define NROWS   (T_STEPS * B_SZ)   // 32768
#define RSTR    68                 // step reduction stride (floats)
#define LSTR    17                 // loss reduction stride (floats)
#define NGRP    16                 // row groups (16 batch rows each)
#define NCB     16                 // col blocks per group (64 cols each)
#define TSLOT   (T_STEPS + 1)      // counter slots per group (incl. plane-127 done)

__device__ __forceinline__ float fast_tanh(float x) {
    float e = __expf(2.0f * x);
    return 1.0f - 2.0f / (e + 1.0f);   // exact at +-inf, no NaN
}

__device__ __forceinline__ bf16x8 cvt_bf16x8(float4 a, float4 b) {
    bf16x8 r;
    r[0] = (bf16)a.x; r[1] = (bf16)a.y; r[2] = (bf16)a.z; r[3] = (bf16)a.w;
    r[4] = (bf16)b.x; r[5] = (bf16)b.y; r[6] = (bf16)b.z; r[7] = (bf16)b.w;
    return r;
}

// ---------------- one-shot prep: all three fp32->bf16 transposes -------------------
__global__ __launch_bounds__(256) void k_prep(
    const float* __restrict__ weights,   // (V+N) x N  = 1280 x 1024
    const float* __restrict__ out_w,     // N x V      = 1024 x 256
    bf16* __restrict__ Wxt,              // 1024 x 256
    bf16* __restrict__ Wht,              // 1024 x 1024
    bf16* __restrict__ Wot)              // 256 x 1024
{
    __shared__ float tile[32][33];
    int id = blockIdx.x;
    const float* src; bf16* dst; int R, C, tr, tc;
    if (id < 256) {            // Wx: rows 0..255 of weights -> Wxt
        src = weights; dst = Wxt; R = V_SZ; C = N_SZ;
        tr = (id & 7) * 32; tc = (id >> 3) * 32;
    } else if (id < 1280) {    // Wh: rows 256..1279 of weights -> Wht
        id -= 256;
        src = weights + (size_t)V_SZ * N_SZ; dst = Wht; R = N_SZ; C = N_SZ;
        tr = (id & 31) * 32; tc = (id >> 5) * 32;
    } else {                   // Wo: out_w -> Wot
        id -= 1280;
        src = out_w; dst = Wot; R = N_SZ; C = V_SZ;
        tr = (id & 31) * 32; tc = (id >> 5) * 32;
    }
    int tx = threadIdx.x & 31;
    int ty = threadIdx.x >> 5;   // 0..7
#pragma unroll
    for (int i = 0; i < 32; i += 8)
        tile[ty + i][tx] = src[(size_t)(tr + ty + i) * C + tc + tx];
    __syncthreads();
#pragma unroll
    for (int i = 0; i < 32; i += 8)
        dst[(size_t)(tc + ty + i) * R + tr + tx] = (bf16)tile[tx][ty + i];
}

// ---------------- persistent recurrence + fused Xproj/loss GEMM + fused lred -------
// Grid 384: blocks [0,256) = rnn role (R14 structure, proven sync: per-block
// counter, 16 arrivals, tid0 poll+arrive, 3 barriers/step); blocks [256,384) =
// lred role (block 256+p handles plane p: poll counters at slot p+1, softmax+loss,
// one atomicAdd). 2 blocks/CU co-residency; lred runs in rnn's latency bubbles.
// Lgu is written write-through (atomic relaxed agent) since it's consumed
// intra-kernel across XCDs. No acquire fences => weights stay L2-hot.
__global__ __launch_bounds__(512, 2) void k_rnn(
    const float* __restrict__ Xf,   // 32768 x 256 fp32 inputs (t-major)
    const bf16* __restrict__ Wxt,   // 1024 x 256  = Wx^T
    const bf16* __restrict__ Wht,   // 1024 x 1024 = Wh^T
    const bf16* __restrict__ Wot,   // 256 x 1024  = Wo^T
    const float* __restrict__ bias,
    const float* __restrict__ labels,
    const float* __restrict__ ob,
    bf16* __restrict__ XH,          // 32768 x 1024 H states
    unsigned int* __restrict__ Lgu, // bf16-pair logits, slab layout [p][c][256][8]
    int* __restrict__ cnt,          // [NGRP * TSLOT], zeroed
    float* __restrict__ out)
{
    __shared__ float red[8 * 16 * RSTR];   // 34.8 KB step K-reduce
    __shared__ float lred[8 * 16 * LSTR];  // 8.7 KB  loss K-reduce
    const int tid  = threadIdx.x;
    const int lane = tid & 63;
    const int w    = tid >> 6;        // 0..7
    const int quad = lane >> 4;
    const int l15  = lane & 15;

    // ================= lred role =================
    if (blockIdx.x >= 256) {
        const int p = blockIdx.x - 256;          // plane 0..127
        // wave w covers rows 32w..32w+31 = groups 2w, 2w+1
        if (lane == 0) {
            const int* c0 = &cnt[(2 * w) * TSLOT + p + 1];
            while (__hip_atomic_load(c0, __ATOMIC_RELAXED, __HIP_MEMORY_SCOPE_AGENT) < NCB)
                __builtin_amdgcn_s_sleep(8);
            const int* c1 = &cnt[(2 * w + 1) * TSLOT + p + 1];
            while (__hip_atomic_load(c1, __ATOMIC_RELAXED, __HIP_MEMORY_SCOPE_AGENT) < NCB)
                __builtin_amdgcn_s_sleep(8);
        }
        asm volatile("" ::: "memory");   // keep loads below the poll
        const bf16* Lg = (const bf16*)Lgu;
        const int cs = lane >> 2;        // vocab slab 0..15
        const int vi = (lane & 3) * 4;   // offset in slab
        const float4 ob4 = *(const float4*)&ob[cs * 16 + vi];
        float wtot = 0.f;
        for (int i = 0; i < 32; ++i) {
            int brow = w * 32 + i;
            bf16x4 lv = *(const bf16x4*)&Lg[(((size_t)p * 16 + cs) * B_SZ + brow) * 16 + vi];
            float l0 = (float)lv.x + ob4.x;
            float l1 = (float)lv.y + ob4.y;
            float l2 = (float)lv.z + ob4.z;
            float l3 = (float)lv.w + ob4.w;
            float mx = fmaxf(fmaxf(l0, l1), fmaxf(l2, l3));
#pragma unroll
            for (int sft = 1; sft < 64; sft <<= 1)
                mx = fmaxf(mx, __shfl_xor(mx, sft, 64));
            float sume = __expf(l0 - mx) + __expf(l1 - mx) + __expf(l2 - mx) + __expf(l3 - mx);
            const float4 lb = *(const float4*)&labels[
                ((size_t)p * B_SZ + brow) * V_SZ + cs * 16 + vi];
            float labs = lb.x + lb.y + lb.z + lb.w;
            float labv = lb.x * l0 + lb.y * l1 + lb.z * l2 + lb.w * l3;
#pragma unroll
            for (int sft = 1; sft < 64; sft <<= 1) {
                sume += __shfl_xor(sume, sft, 64);
                labs += __shfl_xor(labs, sft, 64);
                labv += __shfl_xor(labv, sft, 64);
            }
            float lse = mx + __logf(sume);
            wtot += labs * lse - labv;
        }
        if (lane == 0) red[w] = wtot;
        __syncthreads();
        if (tid == 0) {
            float s = 0.f;
#pragma unroll
            for (int i = 0; i < 8; ++i) s += red[i];
            atomicAdd(out, s * (1.0f / (float)NROWS));
        }
        return;
    }

    // ================= rnn role =================
    const int g  = blockIdx.x >> 4;   // row group
    const int c  = blockIdx.x & 15;   // col block / vocab slab
    const int m0 = g * 16;
    const int n0 = c * 64;
    const int k0 = w * 128;           // K-slice for Wh / Wot GEMMs
    const int v0 = w * 32;            // K-slice for Xproj GEMM (V=256 / 8)
    int* gcnt = cnt + g * TSLOT;

    const bf16* Bp = Wht + (size_t)(n0 + l15) * N_SZ + k0 + quad * 8;
    bf16x8 b[4][4];
#pragma unroll
    for (int nt = 0; nt < 4; ++nt)
#pragma unroll
        for (int kc = 0; kc < 4; ++kc)
            b[nt][kc] = *(const bf16x8*)&Bp[(size_t)(nt * 16) * N_SZ + kc * 32];
    bf16x8 bx[4];
#pragma unroll
    for (int nt = 0; nt < 4; ++nt)
        bx[nt] = *(const bf16x8*)&Wxt[(size_t)(n0 + nt * 16 + l15) * V_SZ + v0 + quad * 8];
    bf16x8 bo[4];
#pragma unroll
    for (int kc = 0; kc < 4; ++kc)
        bo[kc] = *(const bf16x8*)&Wot[(size_t)(c * 16 + l15) * N_SZ + k0 + kc * 32 + quad * 8];

    const int orow = tid >> 5;           // 0..15
    const int ocol = (tid & 31) * 2;     // 0..62
    const float bias0 = bias[n0 + ocol];
    const float bias1 = bias[n0 + ocol + 1];
    const int lrow = w * 2 + (lane >> 3);
    const int lvp  = lane & 7;
    unsigned int* XHu = (unsigned int*)XH;
    const f32x4 zz = {0.f, 0.f, 0.f, 0.f};
    const size_t xin = (size_t)(m0 + l15) * V_SZ + v0 + quad * 8;

    // ---------------- t = 0: H_0 = tanh(Xproj_0 + bias) ----------------
    {
        float4 f0 = *(const float4*)&Xf[xin];
        float4 f1 = *(const float4*)&Xf[xin + 4];
        bf16x8 ax = cvt_bf16x8(f0, f1);
        f32x4 acc[4] = {zz, zz, zz, zz};
#pragma unroll
        for (int nt = 0; nt < 4; ++nt)
            acc[nt] = __builtin_amdgcn_mfma_f32_16x16x32_bf16(ax, bx[nt], acc[nt], 0, 0, 0);
#pragma unroll
        for (int nt = 0; nt < 4; ++nt)
#pragma unroll
            for (int r = 0; r < 4; ++r)
                red[(w * 16 + quad * 4 + r) * RSTR + nt * 16 + l15] = acc[nt][r];
        __syncthreads();
        float s0 = bias0, s1 = bias1;
#pragma unroll
        for (int w2 = 0; w2 < 8; ++w2) {
            float2 v = *(const float2*)&red[(w2 * 16 + orow) * RSTR + ocol];
            s0 += v.x; s1 += v.y;
        }
        bf16 r0 = (bf16)fast_tanh(s0);
        bf16 r1 = (bf16)fast_tanh(s1);
        unsigned int outw = (unsigned int)__builtin_bit_cast(unsigned short, r0)
                          | ((unsigned int)__builtin_bit_cast(unsigned short, r1) << 16);
        size_t oidx = (((size_t)m0 + orow) * N_SZ + n0 + ocol) >> 1;
        __hip_atomic_store(&XHu[oidx], outw, __ATOMIC_RELAXED, __HIP_MEMORY_SCOPE_AGENT);
        asm volatile("s_waitcnt vmcnt(0)" ::: "memory");
        __syncthreads();
        if (tid == 0)
            __hip_atomic_fetch_add(&gcnt[0], 1, __ATOMIC_RELAXED, __HIP_MEMORY_SCOPE_AGENT);
    }

    // ---------------- t = 1 .. 127 ----------------
    for (int t = 1; t < T_STEPS; ++t) {
        float4 f0 = *(const float4*)&Xf[(size_t)t * B_SZ * V_SZ + xin];
        float4 f1 = *(const float4*)&Xf[(size_t)t * B_SZ * V_SZ + xin + 4];

        if (tid == 0) {
            while (__hip_atomic_load(&gcnt[t - 1], __ATOMIC_RELAXED,
                                     __HIP_MEMORY_SCOPE_AGENT) < NCB)
                __builtin_amdgcn_s_sleep(1);
        }
        __syncthreads();

        const bf16* Ap = XH + ((size_t)(t - 1) * B_SZ + m0 + l15) * N_SZ + k0 + quad * 8;
        bf16x8 a[4];
#pragma unroll
        for (int kc = 0; kc < 4; ++kc)
            a[kc] = *(const bf16x8*)&Ap[kc * 32];

        bf16x8 ax = cvt_bf16x8(f0, f1);
        f32x4 acc[4] = {zz, zz, zz, zz};
#pragma unroll
        for (int nt = 0; nt < 4; ++nt)
            acc[nt] = __builtin_amdgcn_mfma_f32_16x16x32_bf16(ax, bx[nt], acc[nt], 0, 0, 0);
#pragma unroll
        for (int kc = 0; kc < 4; ++kc)
#pragma unroll
            for (int nt = 0; nt < 4; ++nt)
                acc[nt] = __builtin_amdgcn_mfma_f32_16x16x32_bf16(a[kc], b[nt][kc],
                                                                  acc[nt], 0, 0, 0);
        f32x4 lacc = zz;
#pragma unroll
        for (int kc = 0; kc < 4; ++kc)
            lacc = __builtin_amdgcn_mfma_f32_16x16x32_bf16(a[kc], bo[kc], lacc, 0, 0, 0);

#pragma unroll
        for (int nt = 0; nt < 4; ++nt)
#pragma unroll
            for (int r = 0; r < 4; ++r)
                red[(w * 16 + quad * 4 + r) * RSTR + nt * 16 + l15] = acc[nt][r];
#pragma unroll
        for (int r = 0; r < 4; ++r)
            lred[(w * 16 + quad * 4 + r) * LSTR + l15] = lacc[r];
        __syncthreads();

        float s0 = bias0, s1 = bias1;
#pragma unroll
        for (int w2 = 0; w2 < 8; ++w2) {
            float2 v = *(const float2*)&red[(w2 * 16 + orow) * RSTR + ocol];
            s0 += v.x; s1 += v.y;
        }
        bf16 r0 = (bf16)fast_tanh(s0);
        bf16 r1 = (bf16)fast_tanh(s1);
        unsigned int outw = (unsigned int)__builtin_bit_cast(unsigned short, r0)
                          | ((unsigned int)__builtin_bit_cast(unsigned short, r1) << 16);
        size_t oidx = (((size_t)t * B_SZ + m0 + orow) * N_SZ + n0 + ocol) >> 1;
        __hip_atomic_store(&XHu[oidx], outw, __ATOMIC_RELAXED, __HIP_MEMORY_SCOPE_AGENT);

        if (lane < 16) {
            float sa = 0.f, sb = 0.f;
#pragma unroll
            for (int w2 = 0; w2 < 8; ++w2) {
                sa += lred[(w2 * 16 + lrow) * LSTR + lvp * 2];
                sb += lred[(w2 * 16 + lrow) * LSTR + lvp * 2 + 1];
            }
            bf16 pa = (bf16)sa, pb = (bf16)sb;
            unsigned int pw = (unsigned int)__builtin_bit_cast(unsigned short, pa)
                            | ((unsigned int)__builtin_bit_cast(unsigned short, pb) << 16);
            // write-through: consumed intra-kernel by lred role on other XCDs
            __hip_atomic_store(&Lgu[(((size_t)(t - 1) * 16 + c) * B_SZ + m0 + lrow) * 8 + lvp],
                               pw, __ATOMIC_RELAXED, __HIP_MEMORY_SCOPE_AGENT);
        }

        asm volatile("s_waitcnt vmcnt(0)" ::: "memory");
        __syncthreads();
        if (tid == 0)
            __hip_atomic_fetch_add(&gcnt[t], 1, __ATOMIC_RELAXED, __HIP_MEMORY_SCOPE_AGENT);
    }

    // ---------------- tail: loss GEMM for plane 127, then arrive slot 128 ----------
    if (tid == 0) {
        while (__hip_atomic_load(&gcnt[T_STEPS - 1], __ATOMIC_RELAXED,
                                 __HIP_MEMORY_SCOPE_AGENT) < NCB)
            __builtin_amdgcn_s_sleep(1);
    }
    __syncthreads();
    {
        const bf16* Ap = XH + ((size_t)(T_STEPS - 1) * B_SZ + m0 + l15) * N_SZ + k0 + quad * 8;
        bf16x8 a[4];
#pragma unroll
        for (int kc = 0; kc < 4; ++kc)
            a[kc] = *(const bf16x8*)&Ap[kc * 32];
        f32x4 lacc = zz;
#pragma unroll
        for (int kc = 0; kc < 4; ++kc)
            lacc = __builtin_amdgcn_mfma_f32_16x16x32_bf16(a[kc], bo[kc], lacc, 0, 0, 0);
#pragma unroll
        for (int r = 0; r < 4; ++r)
            lred[(w * 16 + quad * 4 + r) * LSTR + l15] = lacc[r];
        __syncthreads();
        if (lane < 16) {
            float sa = 0.f, sb = 0.f;
#pragma unroll
            for (int w2 = 0; w2 < 8; ++w2) {
                sa += lred[(w2 * 16 + lrow) * LSTR + lvp * 2];
                sb += lred[(w2 * 16 + lrow) * LSTR + lvp * 2 + 1];
            }
            bf16 pa = (bf16)sa, pb = (bf16)sb;
            unsigned int pw = (unsigned int)__builtin_bit_cast(unsigned short, pa)
                            | ((unsigned int)__builtin_bit_cast(unsigned short, pb) << 16);
            __hip_atomic_store(&Lgu[(((size_t)(T_STEPS - 1) * 16 + c) * B_SZ + m0 + lrow) * 8 + lvp],
                               pw, __ATOMIC_RELAXED, __HIP_MEMORY_SCOPE_AGENT);
        }
        asm volatile("s_waitcnt vmcnt(0)" ::: "memory");
        __syncthreads();
        if (tid == 0)
            __hip_atomic_fetch_add(&gcnt[T_STEPS], 1,
                                   __ATOMIC_RELAXED, __HIP_MEMORY_SCOPE_AGENT);
    }
}

extern "C" void kernel_launch(void* const* d_in, const int* in_sizes, int n_in,
                              void* d_out, int out_size, void* d_ws, size_t ws_size,
                              hipStream_t stream)
{
    const float* inputs  = (const float*)d_in[0];
    const float* labels  = (const float*)d_in[1];
    const float* weights = (const float*)d_in[2];
    const float* bias    = (const float*)d_in[3];
    const float* out_w   = (const float*)d_in[4];
    const float* out_b   = (const float*)d_in[5];
    float* out = (float*)d_out;

    char* ws = (char*)d_ws;
    bf16* XH  = (bf16*)ws;  ws += (size_t)NROWS * N_SZ * 2;   // 64 MB H states
    bf16* Lg  = (bf16*)ws;  ws += (size_t)NROWS * V_SZ * 2;   // 16 MB logits (slab)
    bf16* Wxt = (bf16*)ws;  ws += (size_t)N_SZ * V_SZ * 2;    // 0.5 MB (Wx^T)
    bf16* Wht = (bf16*)ws;  ws += (size_t)N_SZ * N_SZ * 2;    // 2 MB   (Wh^T)
    bf16* Wot = (bf16*)ws;  ws += (size_t)V_SZ * N_SZ * 2;    // 0.5 MB (Wo^T)
    int*  cnt = (int*)ws;   ws += (size_t)NGRP * TSLOT * 4;   // 8.3 KB sync counters

    hipMemsetAsync(out, 0, sizeof(float), stream);
    hipMemsetAsync(cnt, 0, (size_t)NGRP * TSLOT * 4, stream);

    k_prep<<<dim3(1536), 256, 0, stream>>>(weights, out_w, Wxt, Wht, Wot);

    k_rnn<<<dim3(256 + T_STEPS), 512, 0, stream>>>(inputs, Wxt, Wht, Wot, bias,
                                                   labels, out_b, XH,
                                                   (unsigned int*)Lg, cnt, out);
}